// Round 4
// baseline (674.382 us; speedup 1.0000x reference)
//
#include <hip/hip_runtime.h>

#define NB 16
#define SEQ 4096
#define DIMC 1024
#define NH 16
#define DH 64
#define NC 64   // chunks per batch
#define RPC 64  // rows per chunk (== 64 lanes: lane r owns row r's logits)

// ws layout (floats):
#define OFF_WTIL  0          // [16][16][1024]     262144
#define OFF_P     262144     // [16][4096][16]     1048576  (p = exp(logit - m_chunk))
#define OFF_PMAX  1310720    // [16][64][16]       16384
#define OFF_LC    1327104    // [16][64][16]       16384
#define OFF_SCALE 1343488    // [16][64][16]       16384    (exp(m-M)/L)
#define OFF_HO    1359872    // [16][1024]         16384
#define OFF_Y     1376256    // [16][64][16][1024] 16777216
// total 18153472 floats = 72.6 MB

// ---------- k_prep: q_h = x[b,0,:] @ Wq[:,hslice]; wtil[b][h][c] = 0.125 * Wk[c,hslice].q_h
__global__ __launch_bounds__(256) void k_prep(const float* __restrict__ x,
                                              const float* __restrict__ Wq,
                                              const float* __restrict__ Wk,
                                              float* __restrict__ wtil) {
  const int h = blockIdx.x, b = blockIdx.y, t = threadIdx.x;
  const int dd = t & 63, g = t >> 6;
  const float* x0 = x + (size_t)b * SEQ * DIMC;
  __shared__ float red[256];
  __shared__ float qs[64];
  float a = 0.f;
  const float* wq = Wq + h * DH + dd;
  #pragma unroll 4
  for (int c = g * 256; c < g * 256 + 256; ++c)
    a = fmaf(x0[c], wq[(size_t)c * DIMC], a);
  red[t] = a;
  __syncthreads();
  if (t < 64) qs[t] = red[t] + red[64 + t] + red[128 + t] + red[192 + t];
  __syncthreads();
  const float qd = qs[dd];
  float* wt = wtil + ((size_t)b * NH + h) * DIMC;
  const float* wk = Wk + h * DH + dd;
  for (int c = g * 256; c < g * 256 + 256; ++c) {
    float p = wk[(size_t)c * DIMC] * qd;
    #pragma unroll
    for (int o = 1; o < 64; o <<= 1) p += __shfl_xor(p, o);
    if (dd == 0) wt[c] = p * 0.125f;
  }
}

__device__ __forceinline__ float dot16(const float4* xv, const float4* wv) {
  float s = 0.f;
  #pragma unroll
  for (int i = 0; i < 4; ++i) {
    s = fmaf(xv[i].x, wv[i].x, s); s = fmaf(xv[i].y, wv[i].y, s);
    s = fmaf(xv[i].z, wv[i].z, s); s = fmaf(xv[i].w, wv[i].w, s);
  }
  return s;
}

// ---------- k_logit: p = exp(logit - m_chunk), pmax, Lc. 64-row chunks, wave w -> heads 4w..4w+3.
__global__ __launch_bounds__(256) void k_logit(const float* __restrict__ x,
                                               const float* __restrict__ wtil,
                                               float* __restrict__ p,
                                               float* __restrict__ pmax,
                                               float* __restrict__ Lc) {
  const int nc = blockIdx.x, b = blockIdx.y, t = threadIdx.x;
  const int w = t >> 6, l = t & 63;
  const float4* wt4 = (const float4*)wtil + ((size_t)b * NH + w * 4) * 256;
  float4 wv[4][4];
  #pragma unroll
  for (int h = 0; h < 4; ++h)
    #pragma unroll
    for (int i = 0; i < 4; ++i) wv[h][i] = wt4[h * 256 + i * 64 + l];
  const float4* x4 = (const float4*)x + ((size_t)b * SEQ + nc * RPC) * 256;
  float4 va = make_float4(0.f, 0.f, 0.f, 0.f);  // lane l captures row l's 4 logits

  for (int r = 0; r < RPC; r += 2) {
    float4 xa[4], xb[4];
    #pragma unroll
    for (int i = 0; i < 4; ++i) xa[i] = x4[r * 256 + i * 64 + l];
    #pragma unroll
    for (int i = 0; i < 4; ++i) xb[i] = x4[(r + 1) * 256 + i * 64 + l];
    float4 sa, sb;
    sa.x = dot16(xa, wv[0]); sa.y = dot16(xa, wv[1]);
    sa.z = dot16(xa, wv[2]); sa.w = dot16(xa, wv[3]);
    sb.x = dot16(xb, wv[0]); sb.y = dot16(xb, wv[1]);
    sb.z = dot16(xb, wv[2]); sb.w = dot16(xb, wv[3]);
    #pragma unroll
    for (int o = 1; o < 64; o <<= 1) {
      sa.x += __shfl_xor(sa.x, o); sa.y += __shfl_xor(sa.y, o);
      sa.z += __shfl_xor(sa.z, o); sa.w += __shfl_xor(sa.w, o);
      sb.x += __shfl_xor(sb.x, o); sb.y += __shfl_xor(sb.y, o);
      sb.z += __shfl_xor(sb.z, o); sb.w += __shfl_xor(sb.w, o);
    }
    if (l == r) va = sa;
    if (l == r + 1) va = sb;
  }

  // per-chunk max over rows (= over lanes), exp, sum — all in-wave
  float4 m4 = va;
  #pragma unroll
  for (int o = 1; o < 64; o <<= 1) {
    m4.x = fmaxf(m4.x, __shfl_xor(m4.x, o)); m4.y = fmaxf(m4.y, __shfl_xor(m4.y, o));
    m4.z = fmaxf(m4.z, __shfl_xor(m4.z, o)); m4.w = fmaxf(m4.w, __shfl_xor(m4.w, o));
  }
  float4 pv;
  pv.x = __expf(va.x - m4.x); pv.y = __expf(va.y - m4.y);
  pv.z = __expf(va.z - m4.z); pv.w = __expf(va.w - m4.w);
  float4 s4 = pv;
  #pragma unroll
  for (int o = 1; o < 64; o <<= 1) {
    s4.x += __shfl_xor(s4.x, o); s4.y += __shfl_xor(s4.y, o);
    s4.z += __shfl_xor(s4.z, o); s4.w += __shfl_xor(s4.w, o);
  }
  // lane l writes row (nc*64+l), heads w*4..w*4+3 (16B-aligned)
  ((float4*)(p + ((size_t)b * SEQ + (size_t)nc * RPC + l) * NH))[w] = pv;
  if (l == 0) {
    ((float4*)(pmax + ((size_t)b * NC + nc) * NH))[w] = m4;
    ((float4*)(Lc + ((size_t)b * NC + nc) * NH))[w] = s4;
  }
}

// ---------- k_m: M[b][h], scale[b][nc][h] = exp(m_nc - M)/L ; zero ho. 1 block.
__global__ __launch_bounds__(256) void k_m(const float* __restrict__ pmax,
                                           const float* __restrict__ Lc,
                                           float* __restrict__ scale,
                                           float* __restrict__ ho) {
  const int t = threadIdx.x;
  const int b = t >> 4, h = t & 15;
  float M = -3.0e38f;
  #pragma unroll 8
  for (int nc = 0; nc < NC; ++nc)
    M = fmaxf(M, pmax[((size_t)b * NC + nc) * NH + h]);
  float L = 0.f;
  #pragma unroll 8
  for (int nc = 0; nc < NC; ++nc)
    L += Lc[((size_t)b * NC + nc) * NH + h] * __expf(pmax[((size_t)b * NC + nc) * NH + h] - M);
  const float invL = 1.f / L;
  #pragma unroll 8
  for (int nc = 0; nc < NC; ++nc)
    scale[((size_t)b * NC + nc) * NH + h] =
        __expf(pmax[((size_t)b * NC + nc) * NH + h] - M) * invL;
  for (int i = t; i < NB * DIMC; i += 256) ho[i] = 0.f;
}

// ---------- k_acc: y[b][nc][h][c] = sum_{r in chunk} p[r][h] * x[r][c]
__global__ __launch_bounds__(256) void k_acc(const float* __restrict__ x,
                                             const float* __restrict__ p,
                                             float* __restrict__ y) {
  const int nc = blockIdx.x, b = blockIdx.y, t = threadIdx.x;
  float4 acc[16];
  #pragma unroll
  for (int h = 0; h < 16; ++h) acc[h] = make_float4(0.f, 0.f, 0.f, 0.f);
  const float4* x4 = (const float4*)x + ((size_t)b * SEQ + (size_t)nc * RPC) * 256;
  const float4* p4 = (const float4*)(p + ((size_t)b * SEQ + (size_t)nc * RPC) * NH);

  for (int r = 0; r < RPC; r += 2) {
    float4 a0 = p4[r * 4 + 0], a1 = p4[r * 4 + 1], a2 = p4[r * 4 + 2], a3 = p4[r * 4 + 3];
    float4 b0 = p4[r * 4 + 4], b1 = p4[r * 4 + 5], b2 = p4[r * 4 + 6], b3 = p4[r * 4 + 7];
    float4 xva = x4[r * 256 + t];
    float4 xvb = x4[(r + 1) * 256 + t];
    #define ACC(h, ev, xv) acc[h].x = fmaf(ev, xv.x, acc[h].x); acc[h].y = fmaf(ev, xv.y, acc[h].y); \
                           acc[h].z = fmaf(ev, xv.z, acc[h].z); acc[h].w = fmaf(ev, xv.w, acc[h].w)
    ACC(0, a0.x, xva); ACC(1, a0.y, xva); ACC(2, a0.z, xva); ACC(3, a0.w, xva);
    ACC(4, a1.x, xva); ACC(5, a1.y, xva); ACC(6, a1.z, xva); ACC(7, a1.w, xva);
    ACC(8, a2.x, xva); ACC(9, a2.y, xva); ACC(10, a2.z, xva); ACC(11, a2.w, xva);
    ACC(12, a3.x, xva); ACC(13, a3.y, xva); ACC(14, a3.z, xva); ACC(15, a3.w, xva);
    ACC(0, b0.x, xvb); ACC(1, b0.y, xvb); ACC(2, b0.z, xvb); ACC(3, b0.w, xvb);
    ACC(4, b1.x, xvb); ACC(5, b1.y, xvb); ACC(6, b1.z, xvb); ACC(7, b1.w, xvb);
    ACC(8, b2.x, xvb); ACC(9, b2.y, xvb); ACC(10, b2.z, xvb); ACC(11, b2.w, xvb);
    ACC(12, b3.x, xvb); ACC(13, b3.y, xvb); ACC(14, b3.z, xvb); ACC(15, b3.w, xvb);
    #undef ACC
  }
  float4* y4 = (float4*)y + (((size_t)b * NC + nc) * NH) * 256;
  #pragma unroll
  for (int h = 0; h < 16; ++h) y4[h * 256 + t] = acc[h];
}

// ---------- k_comb: ho[b, h*64+d] += sum_c (sum_s y[b,s,h,c]*scale[b,s,h]) * Wv[c, h*64+d]
__global__ __launch_bounds__(256) void k_comb(const float* __restrict__ y,
                                              const float* __restrict__ scale,
                                              const float* __restrict__ Wv,
                                              float* __restrict__ ho) {
  const int cs = blockIdx.x, h = blockIdx.y, b = blockIdx.z, t = threadIdx.x;
  __shared__ float ylds[256];
  __shared__ float red[256];
  const int c = cs * 256 + t;
  float ysum = 0.f;
  #pragma unroll 4
  for (int s = 0; s < NC; ++s)
    ysum = fmaf(y[(((size_t)b * NC + s) * NH + h) * DIMC + c],
                scale[((size_t)b * NC + s) * NH + h], ysum);
  ylds[t] = ysum;
  __syncthreads();
  const int d = t & 63, g = t >> 6;
  float part = 0.f;
  #pragma unroll 4
  for (int k = 0; k < 64; ++k)
    part = fmaf(ylds[g * 64 + k],
                Wv[(size_t)(cs * 256 + g * 64 + k) * DIMC + h * DH + d], part);
  red[t] = part;
  __syncthreads();
  if (t < 64)
    atomicAdd(&ho[(size_t)b * DIMC + h * DH + t],
              red[t] + red[64 + t] + red[128 + t] + red[192 + t]);
}

// ---------- k_out: out[b, j] = ho[b,:] . Wp[:, j] + bp[j]
__global__ __launch_bounds__(256) void k_out(const float* __restrict__ ho,
                                             const float* __restrict__ Wp,
                                             const float* __restrict__ bp,
                                             float* __restrict__ out) {
  const int jc = blockIdx.x, b = blockIdx.y, t = threadIdx.x;
  __shared__ float hs[1024];
  __shared__ float red[256];
  for (int i = t; i < 1024; i += 256) hs[i] = ho[(size_t)b * DIMC + i];
  __syncthreads();
  const int d = t & 63, g = t >> 6;
  const int j = jc * 64 + d;
  float a = 0.f;
  #pragma unroll 8
  for (int i = g * 256; i < g * 256 + 256; ++i)
    a = fmaf(hs[i], Wp[(size_t)i * DIMC + j], a);
  red[t] = a;
  __syncthreads();
  if (t < 64)
    out[(size_t)b * DIMC + jc * 64 + t] =
        red[t] + red[64 + t] + red[128 + t] + red[192 + t] + bp[jc * 64 + t];
}

extern "C" void kernel_launch(void* const* d_in, const int* in_sizes, int n_in,
                              void* d_out, int out_size, void* d_ws, size_t ws_size,
                              hipStream_t stream) {
  const float* x  = (const float*)d_in[0];
  const float* Wq = (const float*)d_in[1];
  const float* Wk = (const float*)d_in[2];
  const float* Wv = (const float*)d_in[3];
  const float* Wp = (const float*)d_in[4];
  const float* bp = (const float*)d_in[5];
  float* out = (float*)d_out;
  float* ws = (float*)d_ws;

  float* wtil  = ws + OFF_WTIL;
  float* p     = ws + OFF_P;
  float* pmax  = ws + OFF_PMAX;
  float* Lc    = ws + OFF_LC;
  float* scale = ws + OFF_SCALE;
  float* ho    = ws + OFF_HO;
  float* y     = ws + OFF_Y;

  k_prep<<<dim3(NH, NB), 256, 0, stream>>>(x, Wq, Wk, wtil);
  k_logit<<<dim3(NC, NB), 256, 0, stream>>>(x, wtil, p, pmax, Lc);
  k_m<<<1, 256, 0, stream>>>(pmax, Lc, scale, ho);
  k_acc<<<dim3(NC, NB), 256, 0, stream>>>(x, p, y);
  k_comb<<<dim3(4, NH, NB), 256, 0, stream>>>(y, scale, Wv, ho);
  k_out<<<dim3(16, NB), 256, 0, stream>>>(ho, Wp, bp, out);
}

// Round 5
// 505.054 us; speedup vs baseline: 1.3353x; 1.3353x over previous
//
#include <hip/hip_runtime.h>

#define NB 16
#define SEQ 4096
#define DIMC 1024
#define NH 16
#define DH 64
#define NC 64   // chunks per batch
#define RPC 64  // rows per chunk (lane r owns row r's logits in phase 1)

// ws layout (floats):
#define OFF_Q    0          // [16][1024]          16384
#define OFF_WTIL 16384      // [16][16][1024]      262144
#define OFF_PMAX 278528     // [16][64][16]        16384
#define OFF_LC   294912     // [16][64][16]        16384
#define OFF_HO4  311296     // [4][16][1024]       65536
#define OFF_Y    376832     // [16][64][16][1024]  16777216
// total 17154048 floats = 68.6 MB

// ---------- kq: q[b][j] = x[b,0,:] . Wq[:,j]   (grid 16 jc x 16 b)
__global__ __launch_bounds__(256) void kq(const float* __restrict__ x,
                                          const float* __restrict__ Wq,
                                          float* __restrict__ qws) {
  const int jc = blockIdx.x, b = blockIdx.y, t = threadIdx.x;
  const int d = t & 63, g = t >> 6;
  const int j = jc * 64 + d;
  const float* x0 = x + (size_t)b * SEQ * DIMC;
  __shared__ float red[256];
  float a = 0.f;
  #pragma unroll 8
  for (int c = g * 256; c < g * 256 + 256; ++c)
    a = fmaf(x0[c], Wq[(size_t)c * DIMC + j], a);
  red[t] = a;
  __syncthreads();
  if (t < 64)
    qws[b * DIMC + jc * 64 + t] = red[t] + red[64 + t] + red[128 + t] + red[192 + t];
}

// ---------- kw: wtil[b][h][c] = 0.125 * Wk[c, h*64: h*64+64] . q[b, h*64: h*64+64]
// Lane l owns cols l*16..l*16+15 (head h = l>>2). Reduce over 4 lanes only.
__global__ __launch_bounds__(256) void kw(const float* __restrict__ Wk,
                                          const float* __restrict__ qws,
                                          float* __restrict__ wtil) {
  const int cb = blockIdx.x, b = blockIdx.y, t = threadIdx.x;
  const int w = t >> 6, l = t & 63;
  float4 qreg[4];
  {
    const float4* q4 = (const float4*)(qws + b * DIMC + l * 16);
    #pragma unroll
    for (int i = 0; i < 4; ++i) qreg[i] = q4[i];
  }
  const int h = l >> 2;
  float* wt = wtil + ((size_t)b * NH + h) * DIMC;
  #pragma unroll 4
  for (int i = 0; i < 16; ++i) {
    const int c = cb * 64 + w * 16 + i;
    const float4* row = (const float4*)(Wk + (size_t)c * DIMC) + l * 4;
    float s = 0.f;
    #pragma unroll
    for (int k = 0; k < 4; ++k) {
      float4 rv = row[k];
      s = fmaf(rv.x, qreg[k].x, s); s = fmaf(rv.y, qreg[k].y, s);
      s = fmaf(rv.z, qreg[k].z, s); s = fmaf(rv.w, qreg[k].w, s);
    }
    s += __shfl_xor(s, 1);
    s += __shfl_xor(s, 2);
    if ((l & 3) == 0) wt[c] = s * 0.125f;
  }
}

__device__ __forceinline__ float dot16(const float4* xv, const float4* wv) {
  float s = 0.f;
  #pragma unroll
  for (int i = 0; i < 4; ++i) {
    s = fmaf(xv[i].x, wv[i].x, s); s = fmaf(xv[i].y, wv[i].y, s);
    s = fmaf(xv[i].z, wv[i].z, s); s = fmaf(xv[i].w, wv[i].w, s);
  }
  return s;
}

// ---------- k_la: fused logits + chunk-local softmax + p@x accumulate.
// Block = (chunk nc, batch b). Phase 1: wave w -> heads 4w..4w+3, lane l captures row l.
// Phase 2: thread t owns col-quad t, x re-read (L3-hot), p from LDS.
__global__ __launch_bounds__(256) void k_la(const float* __restrict__ x,
                                            const float* __restrict__ wtil,
                                            float* __restrict__ y,
                                            float* __restrict__ pmax,
                                            float* __restrict__ Lc) {
  const int nc = blockIdx.x, b = blockIdx.y, t = threadIdx.x;
  const int w = t >> 6, l = t & 63;
  __shared__ float4 pl[RPC][4];  // [row][head-quad]

  const float4* wt4 = (const float4*)wtil + ((size_t)b * NH + w * 4) * 256;
  float4 wv[4][4];
  #pragma unroll
  for (int h = 0; h < 4; ++h)
    #pragma unroll
    for (int i = 0; i < 4; ++i) wv[h][i] = wt4[h * 256 + i * 64 + l];
  const float4* x4 = (const float4*)x + ((size_t)b * SEQ + nc * RPC) * 256;
  float4 va = make_float4(0.f, 0.f, 0.f, 0.f);

  for (int r = 0; r < RPC; r += 2) {
    float4 xa[4], xb[4];
    #pragma unroll
    for (int i = 0; i < 4; ++i) xa[i] = x4[r * 256 + i * 64 + l];
    #pragma unroll
    for (int i = 0; i < 4; ++i) xb[i] = x4[(r + 1) * 256 + i * 64 + l];
    float4 sa, sb;
    sa.x = dot16(xa, wv[0]); sa.y = dot16(xa, wv[1]);
    sa.z = dot16(xa, wv[2]); sa.w = dot16(xa, wv[3]);
    sb.x = dot16(xb, wv[0]); sb.y = dot16(xb, wv[1]);
    sb.z = dot16(xb, wv[2]); sb.w = dot16(xb, wv[3]);
    #pragma unroll
    for (int o = 1; o < 64; o <<= 1) {
      sa.x += __shfl_xor(sa.x, o); sa.y += __shfl_xor(sa.y, o);
      sa.z += __shfl_xor(sa.z, o); sa.w += __shfl_xor(sa.w, o);
      sb.x += __shfl_xor(sb.x, o); sb.y += __shfl_xor(sb.y, o);
      sb.z += __shfl_xor(sb.z, o); sb.w += __shfl_xor(sb.w, o);
    }
    if (l == r) va = sa;
    if (l == r + 1) va = sb;
  }

  // chunk-local max / exp / sum (over rows == lanes)
  float4 m4 = va;
  #pragma unroll
  for (int o = 1; o < 64; o <<= 1) {
    m4.x = fmaxf(m4.x, __shfl_xor(m4.x, o)); m4.y = fmaxf(m4.y, __shfl_xor(m4.y, o));
    m4.z = fmaxf(m4.z, __shfl_xor(m4.z, o)); m4.w = fmaxf(m4.w, __shfl_xor(m4.w, o));
  }
  float4 pv;
  pv.x = __expf(va.x - m4.x); pv.y = __expf(va.y - m4.y);
  pv.z = __expf(va.z - m4.z); pv.w = __expf(va.w - m4.w);
  float4 s4 = pv;
  #pragma unroll
  for (int o = 1; o < 64; o <<= 1) {
    s4.x += __shfl_xor(s4.x, o); s4.y += __shfl_xor(s4.y, o);
    s4.z += __shfl_xor(s4.z, o); s4.w += __shfl_xor(s4.w, o);
  }
  pl[l][w] = pv;
  if (l == 0) {
    ((float4*)(pmax + ((size_t)b * NC + nc) * NH))[w] = m4;
    ((float4*)(Lc + ((size_t)b * NC + nc) * NH))[w] = s4;
  }
  __syncthreads();

  // phase 2: y[b][nc][h][col-quad t] = sum_r p[r][h] * x[r][quad t]
  float4 acc[16];
  #pragma unroll
  for (int h = 0; h < 16; ++h) acc[h] = make_float4(0.f, 0.f, 0.f, 0.f);
  for (int r = 0; r < RPC; r += 2) {
    float4 a0 = pl[r][0], a1 = pl[r][1], a2 = pl[r][2], a3 = pl[r][3];
    float4 b0 = pl[r + 1][0], b1 = pl[r + 1][1], b2 = pl[r + 1][2], b3 = pl[r + 1][3];
    float4 xva = x4[r * 256 + t];
    float4 xvb = x4[(r + 1) * 256 + t];
    #define ACC(h, ev, xv) acc[h].x = fmaf(ev, xv.x, acc[h].x); acc[h].y = fmaf(ev, xv.y, acc[h].y); \
                           acc[h].z = fmaf(ev, xv.z, acc[h].z); acc[h].w = fmaf(ev, xv.w, acc[h].w)
    ACC(0, a0.x, xva); ACC(1, a0.y, xva); ACC(2, a0.z, xva); ACC(3, a0.w, xva);
    ACC(4, a1.x, xva); ACC(5, a1.y, xva); ACC(6, a1.z, xva); ACC(7, a1.w, xva);
    ACC(8, a2.x, xva); ACC(9, a2.y, xva); ACC(10, a2.z, xva); ACC(11, a2.w, xva);
    ACC(12, a3.x, xva); ACC(13, a3.y, xva); ACC(14, a3.z, xva); ACC(15, a3.w, xva);
    ACC(0, b0.x, xvb); ACC(1, b0.y, xvb); ACC(2, b0.z, xvb); ACC(3, b0.w, xvb);
    ACC(4, b1.x, xvb); ACC(5, b1.y, xvb); ACC(6, b1.z, xvb); ACC(7, b1.w, xvb);
    ACC(8, b2.x, xvb); ACC(9, b2.y, xvb); ACC(10, b2.z, xvb); ACC(11, b2.w, xvb);
    ACC(12, b3.x, xvb); ACC(13, b3.y, xvb); ACC(14, b3.z, xvb); ACC(15, b3.w, xvb);
    #undef ACC
  }
  float4* y4 = (float4*)y + (((size_t)b * NC + nc) * NH) * 256;
  #pragma unroll
  for (int h = 0; h < 16; ++h) y4[h * 256 + t] = acc[h];
}

// ---------- k_comb: per (cs,h,b): scale from pmax/Lc in-block, ysum over chunks, x Wv slice
__global__ __launch_bounds__(256) void k_comb(const float* __restrict__ y,
                                              const float* __restrict__ pmax,
                                              const float* __restrict__ Lc,
                                              const float* __restrict__ Wv,
                                              float* __restrict__ ho4) {
  const int cs = blockIdx.x, h = blockIdx.y, b = blockIdx.z, t = threadIdx.x;
  __shared__ float sc[NC];
  __shared__ float ylds[256];
  __shared__ float red[256];
  if (t < 64) {
    float mt = pmax[((size_t)b * NC + t) * NH + h];
    float lt = Lc[((size_t)b * NC + t) * NH + h];
    float M = mt;
    #pragma unroll
    for (int o = 1; o < 64; o <<= 1) M = fmaxf(M, __shfl_xor(M, o));
    float e = __expf(mt - M);
    float L = lt * e;
    #pragma unroll
    for (int o = 1; o < 64; o <<= 1) L += __shfl_xor(L, o);
    sc[t] = e / L;
  }
  __syncthreads();
  const int c = cs * 256 + t;
  float ysum = 0.f;
  #pragma unroll 8
  for (int s = 0; s < NC; ++s)
    ysum = fmaf(y[(((size_t)b * NC + s) * NH + h) * DIMC + c], sc[s], ysum);
  ylds[t] = ysum;
  __syncthreads();
  const int d = t & 63, g = t >> 6;
  float part = 0.f;
  #pragma unroll 4
  for (int k = 0; k < 64; ++k)
    part = fmaf(ylds[g * 64 + k],
                Wv[(size_t)(cs * 256 + g * 64 + k) * DIMC + h * DH + d], part);
  red[t] = part;
  __syncthreads();
  if (t < 64)
    ho4[((size_t)cs * NB + b) * DIMC + h * DH + t] =
        red[t] + red[64 + t] + red[128 + t] + red[192 + t];
}

// ---------- k_out: out[b, j] = (sum_cs ho4[cs][b][:]) . Wp[:, j] + bp[j]
__global__ __launch_bounds__(256) void k_out(const float* __restrict__ ho4,
                                             const float* __restrict__ Wp,
                                             const float* __restrict__ bp,
                                             float* __restrict__ out) {
  const int jc = blockIdx.x, b = blockIdx.y, t = threadIdx.x;
  __shared__ float hs[1024];
  __shared__ float red[256];
  for (int i = t; i < 1024; i += 256)
    hs[i] = ho4[(size_t)b * DIMC + i] + ho4[(size_t)(NB + b) * DIMC + i] +
            ho4[(size_t)(2 * NB + b) * DIMC + i] + ho4[(size_t)(3 * NB + b) * DIMC + i];
  __syncthreads();
  const int d = t & 63, g = t >> 6;
  const int j = jc * 64 + d;
  float a = 0.f;
  #pragma unroll 8
  for (int i = g * 256; i < g * 256 + 256; ++i)
    a = fmaf(hs[i], Wp[(size_t)i * DIMC + j], a);
  red[t] = a;
  __syncthreads();
  if (t < 64)
    out[(size_t)b * DIMC + jc * 64 + t] =
        red[t] + red[64 + t] + red[128 + t] + red[192 + t] + bp[jc * 64 + t];
}

extern "C" void kernel_launch(void* const* d_in, const int* in_sizes, int n_in,
                              void* d_out, int out_size, void* d_ws, size_t ws_size,
                              hipStream_t stream) {
  const float* x  = (const float*)d_in[0];
  const float* Wq = (const float*)d_in[1];
  const float* Wk = (const float*)d_in[2];
  const float* Wv = (const float*)d_in[3];
  const float* Wp = (const float*)d_in[4];
  const float* bp = (const float*)d_in[5];
  float* out = (float*)d_out;
  float* ws = (float*)d_ws;

  float* qws  = ws + OFF_Q;
  float* wtil = ws + OFF_WTIL;
  float* pmax = ws + OFF_PMAX;
  float* Lc   = ws + OFF_LC;
  float* ho4  = ws + OFF_HO4;
  float* y    = ws + OFF_Y;

  kq<<<dim3(16, NB), 256, 0, stream>>>(x, Wq, qws);
  kw<<<dim3(16, NB), 256, 0, stream>>>(Wk, qws, wtil);
  k_la<<<dim3(NC, NB), 256, 0, stream>>>(x, wtil, y, pmax, Lc);
  k_comb<<<dim3(4, NH, NB), 256, 0, stream>>>(y, pmax, Lc, Wv, ho4);
  k_out<<<dim3(16, NB), 256, 0, stream>>>(ho4, Wp, bp, out);
}